// Round 1
// baseline (207.430 us; speedup 1.0000x reference)
//
#include <hip/hip_runtime.h>

#define Hd 512
#define N2d 16
#define Rd 32
#define Ld 4096
#define NCHUNK 64
#define CLEN (Ld / NCHUNK)   // 64

// ---------------------------------------------------------------------------
// Kernel 1: dt[l][h] = softplus( (u[l,:] @ xproj_w^T) @ dt_w^T + dt_b )
// One block handles LT=8 timesteps; 512 blocks total.
// ---------------------------------------------------------------------------
__global__ __launch_bounds__(256) void k_dt(const float* __restrict__ u,
                                            const float* __restrict__ xproj_w,
                                            const float* __restrict__ dt_w,
                                            const float* __restrict__ dt_b,
                                            float* __restrict__ dt_out) {
    __shared__ float u_s[8][Hd];     // 16 KB
    __shared__ float dtu_s[8][Rd];   // 1 KB
    const int t = threadIdx.x;
    const int l0 = blockIdx.x * 8;

    // load u tile [8][512], coalesced
    #pragma unroll
    for (int i = 0; i < 16; ++i) {
        int idx = t + i * 256;                 // 0..4095
        ((float*)u_s)[idx] = u[l0 * Hd + idx];
    }
    __syncthreads();

    // dt_u[l][r] = sum_h u[l][h] * xproj_w[r][h]; 32 r x 8 partial-threads
    const int r = t >> 3;
    const int j = t & 7;
    float part[8];
    #pragma unroll
    for (int l = 0; l < 8; ++l) part[l] = 0.f;
    for (int k = 0; k < 64; ++k) {
        float w = xproj_w[r * Hd + k * 8 + j];
        #pragma unroll
        for (int l = 0; l < 8; ++l) part[l] += u_s[l][k * 8 + j] * w;
    }
    #pragma unroll
    for (int off = 1; off < 8; off <<= 1) {
        #pragma unroll
        for (int l = 0; l < 8; ++l) part[l] += __shfl_xor(part[l], off);
    }
    if (j == 0) {
        #pragma unroll
        for (int l = 0; l < 8; ++l) dtu_s[l][r] = part[l];
    }
    __syncthreads();

    // dt[l][h] = softplus(sum_r dtu[l][r] * dt_w[h][r] + dt_b[h]); 2 h per thread
    #pragma unroll
    for (int hi = 0; hi < 2; ++hi) {
        int h = t + hi * 256;
        float bias = dt_b[h];
        float acc[8];
        #pragma unroll
        for (int l = 0; l < 8; ++l) acc[l] = bias;
        for (int rr = 0; rr < Rd; ++rr) {
            float w = dt_w[h * Rd + rr];
            #pragma unroll
            for (int l = 0; l < 8; ++l) acc[l] += dtu_s[l][rr] * w;
        }
        #pragma unroll
        for (int l = 0; l < 8; ++l) {
            float x = acc[l];
            float sp = fmaxf(x, 0.f) + log1pf(expf(-fabsf(x)));  // stable softplus
            dt_out[(l0 + l) * Hd + h] = sp;
        }
    }
}

// ---------------------------------------------------------------------------
// Per-step ZOH discretization: A_bar = exp(dt*A), ub = u * (exp(z)-1)/z * Bc
// ---------------------------------------------------------------------------
__device__ __forceinline__ void step_ab_ub(float dtv, float uv,
        float Are, float Aim, float Bre, float Bim,
        float& ar, float& ai, float& ubr, float& ubi) {
    float zr = dtv * Are;
    float zi = dtv * Aim;
    float er = __expf(zr);
    float s, c;
    __sincosf(zi, &s, &c);
    ar = er * c;
    ai = er * s;
    float mag2 = zr * zr + zi * zi;
    float br, bi;
    if (mag2 < 1e-8f) {           // |z| < 1e-4  ->  1 + z/2
        br = 1.f + 0.5f * zr;
        bi = 0.5f * zi;
    } else {                      // (exp(z)-1)/z = (A_bar-1)*conj(z)/|z|^2
        float inv = __builtin_amdgcn_rcpf(mag2);
        float nr = ar - 1.f;
        float ni = ai;
        br = (nr * zr + ni * zi) * inv;
        bi = (ni * zr - nr * zi) * inv;
    }
    float tr = uv * br, ti = uv * bi;
    ubr = tr * Bre - ti * Bim;
    ubi = tr * Bim + ti * Bre;
}

// ---------------------------------------------------------------------------
// Kernel 2 (phase 1): per-chunk summaries P = prod A_bar, S = scan w/ h0=0.
// Grid (NCHUNK, H/16); block 256 = 16 h x 16 n.
// ---------------------------------------------------------------------------
__global__ __launch_bounds__(256) void k_chunk(const float* __restrict__ u,
        const float* __restrict__ dt, const float* __restrict__ A_log,
        const float* __restrict__ A_im, const float* __restrict__ B_param,
        float2* __restrict__ Pbuf, float2* __restrict__ Sbuf) {
    const int t = threadIdx.x;
    const int n = t & 15;
    const int h = blockIdx.y * 16 + (t >> 4);
    const int c = blockIdx.x;
    const int hn = h * N2d + n;
    const float Are = -__expf(A_log[hn]);
    const float Aim = A_im[hn];
    const float Bre = B_param[2 * hn];
    const float Bim = B_param[2 * hn + 1];
    float pr = 1.f, pi = 0.f, sr = 0.f, si = 0.f;
    const int lbase = c * CLEN;
    for (int k = 0; k < CLEN; ++k) {
        int l = lbase + k;
        float dtv = dt[l * Hd + h];
        float uv = u[l * Hd + h];
        float ar, ai, ubr, ubi;
        step_ab_ub(dtv, uv, Are, Aim, Bre, Bim, ar, ai, ubr, ubi);
        float nsr = ar * sr - ai * si + ubr;
        float nsi = ar * si + ai * sr + ubi;
        sr = nsr; si = nsi;
        float npr = ar * pr - ai * pi;
        float npi = ar * pi + ai * pr;
        pr = npr; pi = npi;
    }
    int idx = c * (Hd * N2d) + blockIdx.y * 256 + t;  // = c*8192 + h*16 + n
    Pbuf[idx] = make_float2(pr, pi);
    Sbuf[idx] = make_float2(sr, si);
}

// ---------------------------------------------------------------------------
// Kernel 3 (phase 2): sequential combine over chunks -> per-chunk init state.
// 8192 threads, 64 iterations each.
// ---------------------------------------------------------------------------
__global__ __launch_bounds__(256) void k_prefix(const float2* __restrict__ Pbuf,
        const float2* __restrict__ Sbuf, float2* __restrict__ Ibuf) {
    int idx = blockIdx.x * 256 + threadIdx.x;  // 0..8191
    float hr = 0.f, hi = 0.f;
    for (int c = 0; c < NCHUNK; ++c) {
        Ibuf[c * (Hd * N2d) + idx] = make_float2(hr, hi);
        float2 p = Pbuf[c * (Hd * N2d) + idx];
        float2 s = Sbuf[c * (Hd * N2d) + idx];
        float nr = p.x * hr - p.y * hi + s.x;
        float ni = p.x * hi + p.y * hr + s.y;
        hr = nr; hi = ni;
    }
}

// ---------------------------------------------------------------------------
// Kernel 4 (phase 3): re-scan chunks with correct init; emit y.
// y[l,h] = sum_n Re(h_ln * Cc) + u*D ; 16-lane shuffle reduction over n.
// ---------------------------------------------------------------------------
__global__ __launch_bounds__(256) void k_scan(const float* __restrict__ u,
        const float* __restrict__ dt, const float* __restrict__ A_log,
        const float* __restrict__ A_im, const float* __restrict__ B_param,
        const float* __restrict__ C_param, const float* __restrict__ Dp,
        const float2* __restrict__ Ibuf, float* __restrict__ out) {
    const int t = threadIdx.x;
    const int n = t & 15;
    const int h = blockIdx.y * 16 + (t >> 4);
    const int c = blockIdx.x;
    const int hn = h * N2d + n;
    const float Are = -__expf(A_log[hn]);
    const float Aim = A_im[hn];
    const float Bre = B_param[2 * hn];
    const float Bim = B_param[2 * hn + 1];
    const float Cre = C_param[2 * hn];
    const float Cim = C_param[2 * hn + 1];
    const float Dv = Dp[h];
    float2 h0 = Ibuf[c * (Hd * N2d) + blockIdx.y * 256 + t];
    float hr = h0.x, hi = h0.y;
    const int lbase = c * CLEN;
    for (int k = 0; k < CLEN; ++k) {
        int l = lbase + k;
        float dtv = dt[l * Hd + h];
        float uv = u[l * Hd + h];
        float ar, ai, ubr, ubi;
        step_ab_ub(dtv, uv, Are, Aim, Bre, Bim, ar, ai, ubr, ubi);
        float nr = ar * hr - ai * hi + ubr;
        float ni = ar * hi + ai * hr + ubi;
        hr = nr; hi = ni;
        float yv = hr * Cre - hi * Cim;
        #pragma unroll
        for (int off = 1; off < 16; off <<= 1)
            yv += __shfl_xor(yv, off);
        if (n == 0) out[l * Hd + h] = yv + uv * Dv;
    }
}

extern "C" void kernel_launch(void* const* d_in, const int* in_sizes, int n_in,
                              void* d_out, int out_size, void* d_ws, size_t ws_size,
                              hipStream_t stream) {
    const float* u        = (const float*)d_in[0];
    const float* A_log    = (const float*)d_in[1];
    const float* A_im     = (const float*)d_in[2];
    const float* B_param  = (const float*)d_in[3];
    const float* C_param  = (const float*)d_in[4];
    const float* Dp       = (const float*)d_in[5];
    const float* dt_w     = (const float*)d_in[6];
    const float* dt_b     = (const float*)d_in[7];
    const float* xproj_w  = (const float*)d_in[8];

    // workspace layout (floats): dt[L*H] | P[C*8192 f2] | S[C*8192 f2] | I[C*8192 f2]
    float*  ws   = (float*)d_ws;
    float*  dt   = ws;
    float2* Pbuf = (float2*)(ws + (size_t)Ld * Hd);
    float2* Sbuf = Pbuf + (size_t)NCHUNK * Hd * N2d;
    float2* Ibuf = Sbuf + (size_t)NCHUNK * Hd * N2d;
    float*  out  = (float*)d_out;

    k_dt<<<Ld / 8, 256, 0, stream>>>(u, xproj_w, dt_w, dt_b, dt);
    dim3 g2(NCHUNK, Hd / 16);
    k_chunk<<<g2, 256, 0, stream>>>(u, dt, A_log, A_im, B_param, Pbuf, Sbuf);
    k_prefix<<<(Hd * N2d) / 256, 256, 0, stream>>>(Pbuf, Sbuf, Ibuf);
    k_scan<<<g2, 256, 0, stream>>>(u, dt, A_log, A_im, B_param, C_param, Dp, Ibuf, out);
}

// Round 2
// 166.059 us; speedup vs baseline: 1.2491x; 1.2491x over previous
//
#include <hip/hip_runtime.h>

#define Hd 512
#define N2d 16
#define Rd 32
#define Ld 4096
#define NCHUNK 64
#define CLEN (Ld / NCHUNK)   // 64

// ---------------------------------------------------------------------------
// Kernel 0: transpose dt_w[H][R] -> dt_wT[R][H] for coalesced einsum2 loads.
// ---------------------------------------------------------------------------
__global__ __launch_bounds__(256) void k_tw(const float* __restrict__ dt_w,
                                            float* __restrict__ dt_wT) {
    int idx = blockIdx.x * 256 + threadIdx.x;   // 0..16383
    int r = idx >> 9;       // 0..31
    int h = idx & 511;      // 0..511
    dt_wT[idx] = dt_w[h * Rd + r];
}

// ---------------------------------------------------------------------------
// Kernel 1: dt[l][h] = softplus( (u[l,:] @ xproj_w^T) @ dt_w^T + dt_b )
// One block handles 8 timesteps; 512 blocks total.
// ---------------------------------------------------------------------------
__global__ __launch_bounds__(256) void k_dt(const float* __restrict__ u,
                                            const float* __restrict__ xproj_w,
                                            const float* __restrict__ dt_wT,
                                            const float* __restrict__ dt_b,
                                            float* __restrict__ dt_out) {
    __shared__ float u_s[8][Hd];     // 16 KB
    __shared__ float dtu_s[8][Rd];   // 1 KB
    const int t = threadIdx.x;
    const int l0 = blockIdx.x * 8;

    // load u tile [8][512], coalesced
    #pragma unroll
    for (int i = 0; i < 16; ++i) {
        int idx = t + i * 256;                 // 0..4095
        ((float*)u_s)[idx] = u[l0 * Hd + idx];
    }
    __syncthreads();

    // dt_u[l][r] = sum_h u[l][h] * xproj_w[r][h]; 32 r x 8 partial-threads
    const int r = t >> 3;
    const int j = t & 7;
    float part[8];
    #pragma unroll
    for (int l = 0; l < 8; ++l) part[l] = 0.f;
    for (int k = 0; k < 64; ++k) {
        float w = xproj_w[r * Hd + k * 8 + j];
        #pragma unroll
        for (int l = 0; l < 8; ++l) part[l] = fmaf(u_s[l][k * 8 + j], w, part[l]);
    }
    #pragma unroll
    for (int off = 1; off < 8; off <<= 1) {
        #pragma unroll
        for (int l = 0; l < 8; ++l) part[l] += __shfl_xor(part[l], off);
    }
    if (j == 0) {
        #pragma unroll
        for (int l = 0; l < 8; ++l) dtu_s[l][r] = part[l];
    }
    __syncthreads();

    // dt[l][h] = softplus(sum_r dtu[l][r] * dt_wT[r][h] + dt_b[h]); 2 h / thread
    #pragma unroll
    for (int hb = 0; hb < 2; ++hb) {
        int h = hb * 256 + t;
        float bias = dt_b[h];
        float acc[8];
        #pragma unroll
        for (int l = 0; l < 8; ++l) acc[l] = bias;
        for (int rr = 0; rr < Rd; ++rr) {
            float w = dt_wT[rr * Hd + h];      // coalesced, L1-resident
            #pragma unroll
            for (int l = 0; l < 8; ++l) acc[l] = fmaf(dtu_s[l][rr], w, acc[l]);
        }
        #pragma unroll
        for (int l = 0; l < 8; ++l) {
            float x = acc[l];
            float sp = fmaxf(x, 0.f) + log1pf(__expf(-fabsf(x)));  // stable softplus
            dt_out[(l0 + l) * Hd + h] = sp;
        }
    }
}

// ---------------------------------------------------------------------------
// Per-step ZOH: A_bar = exp(dt*A);  ub = (u/dt) * (A_bar - 1) * (Bc/A)
// (BAr,BAi) = Bc/A precomputed per thread. ~12 VALU + 4 trans.
// Small-|z| branch dropped: worst-case cancellation error << threshold.
// ---------------------------------------------------------------------------
__device__ __forceinline__ void step_ab_ub(float dtv, float uv,
        float Are, float Aim, float BAr, float BAi,
        float& ar, float& ai, float& ubr, float& ubi) {
    float er = __expf(dtv * Are);
    float s, c;
    __sincosf(dtv * Aim, &s, &c);
    ar = er * c;
    ai = er * s;
    float us = uv * __builtin_amdgcn_rcpf(dtv);
    float gr = (ar - 1.f) * us;
    float gi = ai * us;
    ubr = fmaf(gr, BAr, -gi * BAi);
    ubi = fmaf(gr, BAi,  gi * BAr);
}

__device__ __forceinline__ void load_consts(const float* A_log, const float* A_im,
        const float* B_param, int hn,
        float& Are, float& Aim, float& BAr, float& BAi) {
    Are = -__expf(A_log[hn]);
    Aim = A_im[hn];
    float Bre = B_param[2 * hn];
    float Bim = B_param[2 * hn + 1];
    float inv = __builtin_amdgcn_rcpf(Are * Are + Aim * Aim);
    BAr = (Bre * Are + Bim * Aim) * inv;   // Bc * conj(A) / |A|^2
    BAi = (Bim * Are - Bre * Aim) * inv;
}

// ---------------------------------------------------------------------------
// Kernel 2 (phase 1): per-chunk summaries P = prod A_bar, S = scan w/ h0=0.
// Grid (NCHUNK, H/16); block 256 = 16 h x 16 n.
// ---------------------------------------------------------------------------
__global__ __launch_bounds__(256) void k_chunk(const float* __restrict__ u,
        const float* __restrict__ dt, const float* __restrict__ A_log,
        const float* __restrict__ A_im, const float* __restrict__ B_param,
        float2* __restrict__ Pbuf, float2* __restrict__ Sbuf) {
    const int t = threadIdx.x;
    const int n = t & 15;
    const int h = blockIdx.y * 16 + (t >> 4);
    const int c = blockIdx.x;
    const int hn = h * N2d + n;
    float Are, Aim, BAr, BAi;
    load_consts(A_log, A_im, B_param, hn, Are, Aim, BAr, BAi);
    float pr = 1.f, pi = 0.f, sr = 0.f, si = 0.f;
    const int lbase = c * CLEN;
    #pragma unroll 8
    for (int k = 0; k < CLEN; ++k) {
        int l = lbase + k;
        float dtv = dt[l * Hd + h];
        float uv = u[l * Hd + h];
        float ar, ai, ubr, ubi;
        step_ab_ub(dtv, uv, Are, Aim, BAr, BAi, ar, ai, ubr, ubi);
        float nsr = fmaf(ar, sr, fmaf(-ai, si, ubr));
        float nsi = fmaf(ar, si, fmaf( ai, sr, ubi));
        sr = nsr; si = nsi;
        float npr = fmaf(ar, pr, -ai * pi);
        float npi = fmaf(ar, pi,  ai * pr);
        pr = npr; pi = npi;
    }
    int idx = c * (Hd * N2d) + blockIdx.y * 256 + t;  // = c*8192 + h*16 + n
    Pbuf[idx] = make_float2(pr, pi);
    Sbuf[idx] = make_float2(sr, si);
}

// ---------------------------------------------------------------------------
// Kernel 3 (phase 2): sequential combine over chunks -> per-chunk init state.
// ---------------------------------------------------------------------------
__global__ __launch_bounds__(256) void k_prefix(const float2* __restrict__ Pbuf,
        const float2* __restrict__ Sbuf, float2* __restrict__ Ibuf) {
    int idx = blockIdx.x * 256 + threadIdx.x;  // 0..8191
    float hr = 0.f, hi = 0.f;
    for (int c = 0; c < NCHUNK; ++c) {
        Ibuf[c * (Hd * N2d) + idx] = make_float2(hr, hi);
        float2 p = Pbuf[c * (Hd * N2d) + idx];
        float2 s = Sbuf[c * (Hd * N2d) + idx];
        float nr = fmaf(p.x, hr, fmaf(-p.y, hi, s.x));
        float ni = fmaf(p.x, hi, fmaf( p.y, hr, s.y));
        hr = nr; hi = ni;
    }
}

// ---------------------------------------------------------------------------
// Kernel 4 (phase 3): re-scan chunks with correct init; emit y.
// ---------------------------------------------------------------------------
__global__ __launch_bounds__(256) void k_scan(const float* __restrict__ u,
        const float* __restrict__ dt, const float* __restrict__ A_log,
        const float* __restrict__ A_im, const float* __restrict__ B_param,
        const float* __restrict__ C_param, const float* __restrict__ Dp,
        const float2* __restrict__ Ibuf, float* __restrict__ out) {
    const int t = threadIdx.x;
    const int n = t & 15;
    const int h = blockIdx.y * 16 + (t >> 4);
    const int c = blockIdx.x;
    const int hn = h * N2d + n;
    float Are, Aim, BAr, BAi;
    load_consts(A_log, A_im, B_param, hn, Are, Aim, BAr, BAi);
    const float Cre = C_param[2 * hn];
    const float Cim = C_param[2 * hn + 1];
    const float Dv = Dp[h];
    float2 h0 = Ibuf[c * (Hd * N2d) + blockIdx.y * 256 + t];
    float hr = h0.x, hi = h0.y;
    const int lbase = c * CLEN;
    #pragma unroll 8
    for (int k = 0; k < CLEN; ++k) {
        int l = lbase + k;
        float dtv = dt[l * Hd + h];
        float uv = u[l * Hd + h];
        float ar, ai, ubr, ubi;
        step_ab_ub(dtv, uv, Are, Aim, BAr, BAi, ar, ai, ubr, ubi);
        float nr = fmaf(ar, hr, fmaf(-ai, hi, ubr));
        float ni = fmaf(ar, hi, fmaf( ai, hr, ubi));
        hr = nr; hi = ni;
        float yv = fmaf(hr, Cre, -hi * Cim);
        #pragma unroll
        for (int off = 1; off < 16; off <<= 1)
            yv += __shfl_xor(yv, off);
        if (n == 0) out[l * Hd + h] = fmaf(uv, Dv, yv);
    }
}

extern "C" void kernel_launch(void* const* d_in, const int* in_sizes, int n_in,
                              void* d_out, int out_size, void* d_ws, size_t ws_size,
                              hipStream_t stream) {
    const float* u        = (const float*)d_in[0];
    const float* A_log    = (const float*)d_in[1];
    const float* A_im     = (const float*)d_in[2];
    const float* B_param  = (const float*)d_in[3];
    const float* C_param  = (const float*)d_in[4];
    const float* Dp       = (const float*)d_in[5];
    const float* dt_w     = (const float*)d_in[6];
    const float* dt_b     = (const float*)d_in[7];
    const float* xproj_w  = (const float*)d_in[8];

    // ws floats: dt[L*H] | P[C*8192 f2] | S[..] | I[..] | dt_wT[R*H]
    float*  ws   = (float*)d_ws;
    float*  dt   = ws;
    float2* Pbuf = (float2*)(ws + (size_t)Ld * Hd);
    float2* Sbuf = Pbuf + (size_t)NCHUNK * Hd * N2d;
    float2* Ibuf = Sbuf + (size_t)NCHUNK * Hd * N2d;
    float*  dt_wT = (float*)(Ibuf + (size_t)NCHUNK * Hd * N2d);
    float*  out  = (float*)d_out;

    k_tw<<<(Rd * Hd) / 256, 256, 0, stream>>>(dt_w, dt_wT);
    k_dt<<<Ld / 8, 256, 0, stream>>>(u, xproj_w, dt_wT, dt_b, dt);
    dim3 g2(NCHUNK, Hd / 16);
    k_chunk<<<g2, 256, 0, stream>>>(u, dt, A_log, A_im, B_param, Pbuf, Sbuf);
    k_prefix<<<(Hd * N2d) / 256, 256, 0, stream>>>(Pbuf, Sbuf, Ibuf);
    k_scan<<<g2, 256, 0, stream>>>(u, dt, A_log, A_im, B_param, C_param, Dp, Ibuf, out);
}

// Round 3
// 164.800 us; speedup vs baseline: 1.2587x; 1.0076x over previous
//
#include <hip/hip_runtime.h>

#define Hd 512
#define N2d 16
#define Rd 32
#define Ld 4096
#define NCHUNK 64
#define CLEN (Ld / NCHUNK)   // 64

// ---------------------------------------------------------------------------
// Kernel 0: transpose dt_w[H][R] -> dt_wT[R][H] for coalesced einsum2 loads.
// ---------------------------------------------------------------------------
__global__ __launch_bounds__(256) void k_tw(const float* __restrict__ dt_w,
                                            float* __restrict__ dt_wT) {
    int idx = blockIdx.x * 256 + threadIdx.x;   // 0..16383
    int r = idx >> 9;       // 0..31
    int h = idx & 511;      // 0..511
    dt_wT[idx] = dt_w[h * Rd + r];
}

// ---------------------------------------------------------------------------
// Kernel 1: dt = softplus(...); writes du[l][h] = (dt, u/dt).
// One block handles 8 timesteps; 512 blocks.
// ---------------------------------------------------------------------------
__global__ __launch_bounds__(256) void k_dt(const float* __restrict__ u,
                                            const float* __restrict__ xproj_w,
                                            const float* __restrict__ dt_wT,
                                            const float* __restrict__ dt_b,
                                            float2* __restrict__ du_out) {
    __shared__ float u_s[8][Hd];     // 16 KB
    __shared__ float dtu_s[8][Rd];   // 1 KB
    const int t = threadIdx.x;
    const int l0 = blockIdx.x * 8;

    #pragma unroll
    for (int i = 0; i < 16; ++i) {
        int idx = t + i * 256;                 // 0..4095
        ((float*)u_s)[idx] = u[l0 * Hd + idx];
    }
    __syncthreads();

    // dt_u[l][r] = sum_h u[l][h] * xproj_w[r][h]; 32 r x 8 partial-threads
    const int r = t >> 3;
    const int j = t & 7;
    float part[8];
    #pragma unroll
    for (int l = 0; l < 8; ++l) part[l] = 0.f;
    for (int k = 0; k < 64; ++k) {
        float w = xproj_w[r * Hd + k * 8 + j];
        #pragma unroll
        for (int l = 0; l < 8; ++l) part[l] = fmaf(u_s[l][k * 8 + j], w, part[l]);
    }
    #pragma unroll
    for (int off = 1; off < 8; off <<= 1) {
        #pragma unroll
        for (int l = 0; l < 8; ++l) part[l] += __shfl_xor(part[l], off);
    }
    if (j == 0) {
        #pragma unroll
        for (int l = 0; l < 8; ++l) dtu_s[l][r] = part[l];
    }
    __syncthreads();

    #pragma unroll
    for (int hb = 0; hb < 2; ++hb) {
        int h = hb * 256 + t;
        float bias = dt_b[h];
        float acc[8];
        #pragma unroll
        for (int l = 0; l < 8; ++l) acc[l] = bias;
        for (int rr = 0; rr < Rd; ++rr) {
            float w = dt_wT[rr * Hd + h];
            #pragma unroll
            for (int l = 0; l < 8; ++l) acc[l] = fmaf(dtu_s[l][rr], w, acc[l]);
        }
        #pragma unroll
        for (int l = 0; l < 8; ++l) {
            float x = acc[l];
            float sp = fmaxf(x, 0.f) + log1pf(__expf(-fabsf(x)));  // softplus
            float uv = u_s[l][h];
            float us = uv * __builtin_amdgcn_rcpf(fmaxf(sp, 1e-30f));
            du_out[(l0 + l) * Hd + h] = make_float2(sp, us);
        }
    }
}

__device__ __forceinline__ void load_consts4(const float* A_log, const float* A_im,
        const float* B_param, int hnb,
        float* Are, float* Aim, float* BAr, float* BAi) {
    #pragma unroll
    for (int j = 0; j < 4; ++j) {
        int hn = hnb + j;
        Are[j] = -__expf(A_log[hn]);
        Aim[j] = A_im[hn];
        float Bre = B_param[2 * hn];
        float Bim = B_param[2 * hn + 1];
        float inv = __builtin_amdgcn_rcpf(Are[j] * Are[j] + Aim[j] * Aim[j]);
        BAr[j] = (Bre * Are[j] + Bim * Aim[j]) * inv;   // Bc*conj(A)/|A|^2
        BAi[j] = (Bim * Are[j] - Bre * Aim[j]) * inv;
    }
}

// ---------------------------------------------------------------------------
// Kernel 2 (phase 1): per-chunk S (scan w/ h0=0) + P = exp(A * sum_dt).
// 4 n per thread. Block 256 = 64 h x 4 quads. Grid (NCHUNK, H/64).
// ---------------------------------------------------------------------------
__global__ __launch_bounds__(256) void k_chunk(const float2* __restrict__ du,
        const float* __restrict__ A_log, const float* __restrict__ A_im,
        const float* __restrict__ B_param,
        float2* __restrict__ Pbuf, float2* __restrict__ Sbuf) {
    const int t = threadIdx.x;
    const int q = t & 3;
    const int h = blockIdx.y * 64 + (t >> 2);
    const int c = blockIdx.x;
    const int hnb = h * N2d + q * 4;
    float Are[4], Aim[4], BAr[4], BAi[4];
    load_consts4(A_log, A_im, B_param, hnb, Are, Aim, BAr, BAi);
    float sr[4] = {0.f, 0.f, 0.f, 0.f}, si[4] = {0.f, 0.f, 0.f, 0.f};
    float sdt = 0.f;
    const int lbase = c * CLEN;
    #pragma unroll 4
    for (int k = 0; k < CLEN; ++k) {
        float2 d = du[(lbase + k) * Hd + h];
        float dtv = d.x, us = d.y;
        sdt += dtv;
        #pragma unroll
        for (int j = 0; j < 4; ++j) {
            float er = __expf(dtv * Are[j]);
            float s, cc;
            __sincosf(dtv * Aim[j], &s, &cc);
            float ar = er * cc, ai = er * s;
            float gr = fmaf(ar, us, -us);       // (ar-1)*us
            float gi = ai * us;
            float nr = fmaf(ar, sr[j], fmaf(-ai, si[j], fmaf(gr, BAr[j], -gi * BAi[j])));
            float ni = fmaf(ar, si[j], fmaf( ai, sr[j], fmaf(gr, BAi[j],  gi * BAr[j])));
            sr[j] = nr; si[j] = ni;
        }
    }
    int base = c * (Hd * N2d) + hnb;
    #pragma unroll
    for (int j = 0; j < 4; ++j) {
        float er = __expf(sdt * Are[j]);
        float s, cc;
        __sincosf(sdt * Aim[j], &s, &cc);
        Pbuf[base + j] = make_float2(er * cc, er * s);
        Sbuf[base + j] = make_float2(sr[j], si[j]);
    }
}

// ---------------------------------------------------------------------------
// Kernel 3 (phase 2): sequential combine over chunks -> per-chunk init state.
// ---------------------------------------------------------------------------
__global__ __launch_bounds__(256) void k_prefix(const float2* __restrict__ Pbuf,
        const float2* __restrict__ Sbuf, float2* __restrict__ Ibuf) {
    int idx = blockIdx.x * 256 + threadIdx.x;  // 0..8191
    float hr = 0.f, hi = 0.f;
    for (int c = 0; c < NCHUNK; ++c) {
        Ibuf[c * (Hd * N2d) + idx] = make_float2(hr, hi);
        float2 p = Pbuf[c * (Hd * N2d) + idx];
        float2 s = Sbuf[c * (Hd * N2d) + idx];
        float nr = fmaf(p.x, hr, fmaf(-p.y, hi, s.x));
        float ni = fmaf(p.x, hi, fmaf( p.y, hr, s.y));
        hr = nr; hi = ni;
    }
}

// ---------------------------------------------------------------------------
// Kernel 4 (phase 3): re-scan chunks with correct init; emit y.
// 4 n per thread; 2-stage shuffle reduce across the 4-thread quad group.
// ---------------------------------------------------------------------------
__global__ __launch_bounds__(256) void k_scan(const float2* __restrict__ du,
        const float* __restrict__ A_log, const float* __restrict__ A_im,
        const float* __restrict__ B_param, const float* __restrict__ C_param,
        const float* __restrict__ Dp, const float2* __restrict__ Ibuf,
        float* __restrict__ out) {
    const int t = threadIdx.x;
    const int q = t & 3;
    const int h = blockIdx.y * 64 + (t >> 2);
    const int c = blockIdx.x;
    const int hnb = h * N2d + q * 4;
    float Are[4], Aim[4], BAr[4], BAi[4], Cre[4], Cim[4];
    load_consts4(A_log, A_im, B_param, hnb, Are, Aim, BAr, BAi);
    #pragma unroll
    for (int j = 0; j < 4; ++j) {
        Cre[j] = C_param[2 * (hnb + j)];
        Cim[j] = C_param[2 * (hnb + j) + 1];
    }
    const float Dv = Dp[h];
    float hr[4], hi[4];
    {
        int base = c * (Hd * N2d) + hnb;
        #pragma unroll
        for (int j = 0; j < 4; ++j) {
            float2 h0 = Ibuf[base + j];
            hr[j] = h0.x; hi[j] = h0.y;
        }
    }
    const int lbase = c * CLEN;
    #pragma unroll 4
    for (int k = 0; k < CLEN; ++k) {
        int l = lbase + k;
        float2 d = du[l * Hd + h];
        float dtv = d.x, us = d.y;
        float yv = 0.f;
        #pragma unroll
        for (int j = 0; j < 4; ++j) {
            float er = __expf(dtv * Are[j]);
            float s, cc;
            __sincosf(dtv * Aim[j], &s, &cc);
            float ar = er * cc, ai = er * s;
            float gr = fmaf(ar, us, -us);
            float gi = ai * us;
            float nr = fmaf(ar, hr[j], fmaf(-ai, hi[j], fmaf(gr, BAr[j], -gi * BAi[j])));
            float ni = fmaf(ar, hi[j], fmaf( ai, hr[j], fmaf(gr, BAi[j],  gi * BAr[j])));
            hr[j] = nr; hi[j] = ni;
            yv = fmaf(nr, Cre[j], yv);
            yv = fmaf(-ni, Cim[j], yv);
        }
        yv += __shfl_xor(yv, 1);
        yv += __shfl_xor(yv, 2);
        if (q == 0) out[l * Hd + h] = fmaf(dtv * us, Dv, yv);
    }
}

extern "C" void kernel_launch(void* const* d_in, const int* in_sizes, int n_in,
                              void* d_out, int out_size, void* d_ws, size_t ws_size,
                              hipStream_t stream) {
    const float* u        = (const float*)d_in[0];
    const float* A_log    = (const float*)d_in[1];
    const float* A_im     = (const float*)d_in[2];
    const float* B_param  = (const float*)d_in[3];
    const float* C_param  = (const float*)d_in[4];
    const float* Dp       = (const float*)d_in[5];
    const float* dt_w     = (const float*)d_in[6];
    const float* dt_b     = (const float*)d_in[7];
    const float* xproj_w  = (const float*)d_in[8];

    // ws floats: du[L*H f2] | P[C*8192 f2] | S[..] | I[..] | dt_wT[R*H]
    float2* du   = (float2*)d_ws;
    float2* Pbuf = du + (size_t)Ld * Hd;
    float2* Sbuf = Pbuf + (size_t)NCHUNK * Hd * N2d;
    float2* Ibuf = Sbuf + (size_t)NCHUNK * Hd * N2d;
    float*  dt_wT = (float*)(Ibuf + (size_t)NCHUNK * Hd * N2d);
    float*  out  = (float*)d_out;

    k_tw<<<(Rd * Hd) / 256, 256, 0, stream>>>(dt_w, dt_wT);
    k_dt<<<Ld / 8, 256, 0, stream>>>(u, xproj_w, dt_wT, dt_b, du);
    dim3 g2(NCHUNK, Hd / 64);
    k_chunk<<<g2, 256, 0, stream>>>(du, A_log, A_im, B_param, Pbuf, Sbuf);
    k_prefix<<<(Hd * N2d) / 256, 256, 0, stream>>>(Pbuf, Sbuf, Ibuf);
    k_scan<<<g2, 256, 0, stream>>>(du, A_log, A_im, B_param, C_param, Dp, Ibuf, out);
}

// Round 4
// 154.258 us; speedup vs baseline: 1.3447x; 1.0683x over previous
//
#include <hip/hip_runtime.h>

#define Hd 512
#define N2d 16
#define Rd 32
#define Ld 4096
#define NCHUNK 128
#define CLEN (Ld / NCHUNK)   // 32
#define NCH (Hd * N2d)       // 8192 chains

// ---------------------------------------------------------------------------
// Kernel 0: transpose dt_w[H][R] -> dt_wT[R][H] for coalesced einsum2 loads.
// ---------------------------------------------------------------------------
__global__ __launch_bounds__(256) void k_tw(const float* __restrict__ dt_w,
                                            float* __restrict__ dt_wT) {
    int idx = blockIdx.x * 256 + threadIdx.x;   // 0..16383
    int r = idx >> 9;
    int h = idx & 511;
    dt_wT[idx] = dt_w[h * Rd + r];
}

// ---------------------------------------------------------------------------
// Kernel 1: dt = softplus(u@xprojT@dtwT + b); writes du[l][h] = (dt, u/dt).
// ---------------------------------------------------------------------------
__global__ __launch_bounds__(256) void k_dt(const float* __restrict__ u,
                                            const float* __restrict__ xproj_w,
                                            const float* __restrict__ dt_wT,
                                            const float* __restrict__ dt_b,
                                            float2* __restrict__ du_out) {
    __shared__ float u_s[8][Hd];
    __shared__ float dtu_s[8][Rd];
    const int t = threadIdx.x;
    const int l0 = blockIdx.x * 8;

    #pragma unroll
    for (int i = 0; i < 16; ++i) {
        int idx = t + i * 256;
        ((float*)u_s)[idx] = u[l0 * Hd + idx];
    }
    __syncthreads();

    const int r = t >> 3;
    const int j = t & 7;
    float part[8];
    #pragma unroll
    for (int l = 0; l < 8; ++l) part[l] = 0.f;
    for (int k = 0; k < 64; ++k) {
        float w = xproj_w[r * Hd + k * 8 + j];
        #pragma unroll
        for (int l = 0; l < 8; ++l) part[l] = fmaf(u_s[l][k * 8 + j], w, part[l]);
    }
    #pragma unroll
    for (int off = 1; off < 8; off <<= 1) {
        #pragma unroll
        for (int l = 0; l < 8; ++l) part[l] += __shfl_xor(part[l], off);
    }
    if (j == 0) {
        #pragma unroll
        for (int l = 0; l < 8; ++l) dtu_s[l][r] = part[l];
    }
    __syncthreads();

    #pragma unroll
    for (int hb = 0; hb < 2; ++hb) {
        int h = hb * 256 + t;
        float bias = dt_b[h];
        float acc[8];
        #pragma unroll
        for (int l = 0; l < 8; ++l) acc[l] = bias;
        for (int rr = 0; rr < Rd; ++rr) {
            float w = dt_wT[rr * Hd + h];
            #pragma unroll
            for (int l = 0; l < 8; ++l) acc[l] = fmaf(dtu_s[l][rr], w, acc[l]);
        }
        #pragma unroll
        for (int l = 0; l < 8; ++l) {
            float x = acc[l];
            float sp = fmaxf(x, 0.f) + log1pf(__expf(-fabsf(x)));  // softplus
            float uv = u_s[l][h];
            float us = uv * __builtin_amdgcn_rcpf(fmaxf(sp, 1e-30f));
            du_out[(l0 + l) * Hd + h] = make_float2(sp, us);
        }
    }
}

// ---------------------------------------------------------------------------
// Shared per-thread constant setup: 4 consecutive n of one h.
// fast == true when Are uniform and Aim arithmetic across the 4 (true for
// S4D init A = -1 + i*n); enables 1exp+2sincos per step instead of 4+4.
// ---------------------------------------------------------------------------
__device__ __forceinline__ bool load_consts4(const float* A_log, const float* A_im,
        const float* B_param, int hnb,
        float* Are, float* Aim, float* BAr, float* BAi) {
    #pragma unroll
    for (int j = 0; j < 4; ++j) {
        int hn = hnb + j;
        Are[j] = -__expf(A_log[hn]);
        Aim[j] = A_im[hn];
        float Bre = B_param[2 * hn];
        float Bim = B_param[2 * hn + 1];
        float inv = __builtin_amdgcn_rcpf(Are[j] * Are[j] + Aim[j] * Aim[j]);
        BAr[j] = (Bre * Are[j] + Bim * Aim[j]) * inv;   // Bc*conj(A)/|A|^2
        BAi[j] = (Bim * Are[j] - Bre * Aim[j]) * inv;
    }
    float d1 = Aim[1] - Aim[0], d2 = Aim[2] - Aim[1], d3 = Aim[3] - Aim[2];
    return (Are[1] == Are[0]) && (Are[2] == Are[0]) && (Are[3] == Are[0]) &&
           (d1 == d2) && (d2 == d3);
}

// ---------------------------------------------------------------------------
// Kernel 2 (phase 1): per-chunk S (scan w/ h0=0) + P = exp(A * sum_dt).
// 4 n per thread. Block 256 = 64 h x 4 quads. Grid (NCHUNK, H/64).
// ---------------------------------------------------------------------------
__global__ __launch_bounds__(256) void k_chunk(const float2* __restrict__ du,
        const float* __restrict__ A_log, const float* __restrict__ A_im,
        const float* __restrict__ B_param,
        float2* __restrict__ Pbuf, float2* __restrict__ Sbuf) {
    const int t = threadIdx.x;
    const int q = t & 3;
    const int h = blockIdx.y * 64 + (t >> 2);
    const int c = blockIdx.x;
    const int hnb = h * N2d + q * 4;
    float Are[4], Aim[4], BAr[4], BAi[4];
    const bool fast = load_consts4(A_log, A_im, B_param, hnb, Are, Aim, BAr, BAi);
    float sr[4] = {0.f, 0.f, 0.f, 0.f}, si[4] = {0.f, 0.f, 0.f, 0.f};
    float sdt = 0.f;
    const int lbase = c * CLEN;
    if (fast) {
        const float Are0 = Are[0], Aim0 = Aim[0], dA = Aim[1] - Aim[0];
        #pragma unroll 4
        for (int k = 0; k < CLEN; ++k) {
            float2 d = du[(lbase + k) * Hd + h];
            float dtv = d.x, us = d.y;
            sdt += dtv;
            float er = __expf(dtv * Are0);
            float s0, c0, sd, cd;
            __sincosf(dtv * Aim0, &s0, &c0);
            __sincosf(dtv * dA, &sd, &cd);
            float ar = er * c0, ai = er * s0;
            #pragma unroll
            for (int j = 0; j < 4; ++j) {
                float gr = fmaf(ar, us, -us);
                float gi = ai * us;
                float nr = fmaf(ar, sr[j], fmaf(-ai, si[j], fmaf(gr, BAr[j], -gi * BAi[j])));
                float ni = fmaf(ar, si[j], fmaf( ai, sr[j], fmaf(gr, BAi[j],  gi * BAr[j])));
                sr[j] = nr; si[j] = ni;
                if (j < 3) {
                    float tr = fmaf(ar, cd, -ai * sd);
                    ai = fmaf(ai, cd, ar * sd);
                    ar = tr;
                }
            }
        }
    } else {
        #pragma unroll 4
        for (int k = 0; k < CLEN; ++k) {
            float2 d = du[(lbase + k) * Hd + h];
            float dtv = d.x, us = d.y;
            sdt += dtv;
            #pragma unroll
            for (int j = 0; j < 4; ++j) {
                float er = __expf(dtv * Are[j]);
                float s, cc;
                __sincosf(dtv * Aim[j], &s, &cc);
                float ar = er * cc, ai = er * s;
                float gr = fmaf(ar, us, -us);
                float gi = ai * us;
                float nr = fmaf(ar, sr[j], fmaf(-ai, si[j], fmaf(gr, BAr[j], -gi * BAi[j])));
                float ni = fmaf(ar, si[j], fmaf( ai, sr[j], fmaf(gr, BAi[j],  gi * BAr[j])));
                sr[j] = nr; si[j] = ni;
            }
        }
    }
    int base = c * NCH + hnb;
    #pragma unroll
    for (int j = 0; j < 4; ++j) {
        float er = __expf(sdt * Are[j]);
        float s, cc;
        __sincosf(sdt * Aim[j], &s, &cc);
        Pbuf[base + j] = make_float2(er * cc, er * s);
        Sbuf[base + j] = make_float2(sr[j], si[j]);
    }
}

// ---------------------------------------------------------------------------
// Kernel 3 (phase 2): sequential combine over chunks -> per-chunk init state.
// Batched loads (8 chunks per vmcnt wait) to amortize memory latency on the
// dependent chain; only 128 waves in flight.
// ---------------------------------------------------------------------------
__global__ __launch_bounds__(256) void k_prefix(const float2* __restrict__ Pbuf,
        const float2* __restrict__ Sbuf, float2* __restrict__ Ibuf) {
    int idx = blockIdx.x * 256 + threadIdx.x;  // 0..8191
    float hr = 0.f, hi = 0.f;
    for (int b = 0; b < NCHUNK / 8; ++b) {
        float2 tp[8], ts[8];
        #pragma unroll
        for (int i = 0; i < 8; ++i) {
            tp[i] = Pbuf[(b * 8 + i) * NCH + idx];
            ts[i] = Sbuf[(b * 8 + i) * NCH + idx];
        }
        #pragma unroll
        for (int i = 0; i < 8; ++i) {
            Ibuf[(b * 8 + i) * NCH + idx] = make_float2(hr, hi);
            float nr = fmaf(tp[i].x, hr, fmaf(-tp[i].y, hi, ts[i].x));
            float ni = fmaf(tp[i].x, hi, fmaf( tp[i].y, hr, ts[i].y));
            hr = nr; hi = ni;
        }
    }
}

// ---------------------------------------------------------------------------
// Kernel 4 (phase 3): re-scan chunks with correct init; emit y.
// ---------------------------------------------------------------------------
__global__ __launch_bounds__(256) void k_scan(const float2* __restrict__ du,
        const float* __restrict__ A_log, const float* __restrict__ A_im,
        const float* __restrict__ B_param, const float* __restrict__ C_param,
        const float* __restrict__ Dp, const float2* __restrict__ Ibuf,
        float* __restrict__ out) {
    const int t = threadIdx.x;
    const int q = t & 3;
    const int h = blockIdx.y * 64 + (t >> 2);
    const int c = blockIdx.x;
    const int hnb = h * N2d + q * 4;
    float Are[4], Aim[4], BAr[4], BAi[4], Cre[4], Cim[4];
    const bool fast = load_consts4(A_log, A_im, B_param, hnb, Are, Aim, BAr, BAi);
    #pragma unroll
    for (int j = 0; j < 4; ++j) {
        Cre[j] = C_param[2 * (hnb + j)];
        Cim[j] = C_param[2 * (hnb + j) + 1];
    }
    const float Dv = Dp[h];
    float hr[4], hi[4];
    {
        int base = c * NCH + hnb;
        #pragma unroll
        for (int j = 0; j < 4; ++j) {
            float2 h0 = Ibuf[base + j];
            hr[j] = h0.x; hi[j] = h0.y;
        }
    }
    const int lbase = c * CLEN;
    if (fast) {
        const float Are0 = Are[0], Aim0 = Aim[0], dA = Aim[1] - Aim[0];
        #pragma unroll 4
        for (int k = 0; k < CLEN; ++k) {
            int l = lbase + k;
            float2 d = du[l * Hd + h];
            float dtv = d.x, us = d.y;
            float er = __expf(dtv * Are0);
            float s0, c0, sd, cd;
            __sincosf(dtv * Aim0, &s0, &c0);
            __sincosf(dtv * dA, &sd, &cd);
            float ar = er * c0, ai = er * s0;
            float yv = 0.f;
            #pragma unroll
            for (int j = 0; j < 4; ++j) {
                float gr = fmaf(ar, us, -us);
                float gi = ai * us;
                float nr = fmaf(ar, hr[j], fmaf(-ai, hi[j], fmaf(gr, BAr[j], -gi * BAi[j])));
                float ni = fmaf(ar, hi[j], fmaf( ai, hr[j], fmaf(gr, BAi[j],  gi * BAr[j])));
                hr[j] = nr; hi[j] = ni;
                yv = fmaf(nr, Cre[j], fmaf(-ni, Cim[j], yv));
                if (j < 3) {
                    float tr = fmaf(ar, cd, -ai * sd);
                    ai = fmaf(ai, cd, ar * sd);
                    ar = tr;
                }
            }
            yv += __shfl_xor(yv, 1);
            yv += __shfl_xor(yv, 2);
            if (q == 0) out[l * Hd + h] = fmaf(dtv * us, Dv, yv);
        }
    } else {
        #pragma unroll 4
        for (int k = 0; k < CLEN; ++k) {
            int l = lbase + k;
            float2 d = du[l * Hd + h];
            float dtv = d.x, us = d.y;
            float yv = 0.f;
            #pragma unroll
            for (int j = 0; j < 4; ++j) {
                float er = __expf(dtv * Are[j]);
                float s, cc;
                __sincosf(dtv * Aim[j], &s, &cc);
                float ar = er * cc, ai = er * s;
                float gr = fmaf(ar, us, -us);
                float gi = ai * us;
                float nr = fmaf(ar, hr[j], fmaf(-ai, hi[j], fmaf(gr, BAr[j], -gi * BAi[j])));
                float ni = fmaf(ar, hi[j], fmaf( ai, hr[j], fmaf(gr, BAi[j],  gi * BAr[j])));
                hr[j] = nr; hi[j] = ni;
                yv = fmaf(nr, Cre[j], fmaf(-ni, Cim[j], yv));
            }
            yv += __shfl_xor(yv, 1);
            yv += __shfl_xor(yv, 2);
            if (q == 0) out[l * Hd + h] = fmaf(dtv * us, Dv, yv);
        }
    }
}

extern "C" void kernel_launch(void* const* d_in, const int* in_sizes, int n_in,
                              void* d_out, int out_size, void* d_ws, size_t ws_size,
                              hipStream_t stream) {
    const float* u        = (const float*)d_in[0];
    const float* A_log    = (const float*)d_in[1];
    const float* A_im     = (const float*)d_in[2];
    const float* B_param  = (const float*)d_in[3];
    const float* C_param  = (const float*)d_in[4];
    const float* Dp       = (const float*)d_in[5];
    const float* dt_w     = (const float*)d_in[6];
    const float* dt_b     = (const float*)d_in[7];
    const float* xproj_w  = (const float*)d_in[8];

    // ws: du[L*H f2] | P[NCHUNK*NCH f2] | S[..] | I[..] | dt_wT[R*H f]
    float2* du   = (float2*)d_ws;
    float2* Pbuf = du + (size_t)Ld * Hd;
    float2* Sbuf = Pbuf + (size_t)NCHUNK * NCH;
    float2* Ibuf = Sbuf + (size_t)NCHUNK * NCH;
    float*  dt_wT = (float*)(Ibuf + (size_t)NCHUNK * NCH);
    float*  out  = (float*)d_out;

    k_tw<<<(Rd * Hd) / 256, 256, 0, stream>>>(dt_w, dt_wT);
    k_dt<<<Ld / 8, 256, 0, stream>>>(u, xproj_w, dt_wT, dt_b, du);
    dim3 g2(NCHUNK, Hd / 64);
    k_chunk<<<g2, 256, 0, stream>>>(du, A_log, A_im, B_param, Pbuf, Sbuf);
    k_prefix<<<NCH / 256, 256, 0, stream>>>(Pbuf, Sbuf, Ibuf);
    k_scan<<<g2, 256, 0, stream>>>(du, A_log, A_im, B_param, C_param, Dp, Ibuf, out);
}